// Round 2
// baseline (412.681 us; speedup 1.0000x reference)
//
#include <hip/hip_runtime.h>

// EdgeFormerINT4Linear via INT8 dynamic quantization:
// y[m,o] = (sum_i xq[m,i]*q[o,i]) * (srow[m]*scale[o]) + bias[o]
// Round 3: true 8-phase 256x256 schedule (T3+T4 counted vmcnt(6), T5 setprio,
// T1 XCD swizzle), derived need-ordered half-tile staging:
//   A'0 = rows {0-63,128-191} (mh0), A'1 = {64-127,192-255} (mh1)
//   B'0 = rows ==0..31 mod 64 (nh0), B'1 = rest (nh1)
// Per tile t: p1{ldA'0+B'0, stage A'1(t+1)->other buf}, p2{ldB'1, stage
// A'0(t+2)}, p3{ldA'1, stage B'0(t+2)}, p4{stage B'1(t+2), vmcnt(6)}.
// Slot-death vs stage-issue verified race-free against post-MFMA barriers.

#define M_ROWS 8192
#define N_COLS 4096
#define K_DIM  4096
#define NT     (K_DIM / 128)   // 32 K-tiles of 128 bytes

typedef int int32x4 __attribute__((ext_vector_type(4)));

__device__ __forceinline__ void async16(const void* g, void* l) {
  __builtin_amdgcn_global_load_lds(
      (const __attribute__((address_space(1))) void*)g,
      (__attribute__((address_space(3))) void*)l,
      16 /*bytes*/, 0 /*offset*/, 0 /*aux*/);
}

// ---- fused prepass ----
// blocks [0, M_ROWS): per-row symmetric int8 quant of x (256 thr x 16 elems)
// blocks [M_ROWS, ...): q int32 -> int8 pack (1 int4/thread)
__global__ __launch_bounds__(256) void prep_kernel(const float4* __restrict__ x,
                                                   int* __restrict__ xq,
                                                   float* __restrict__ srow,
                                                   const int4* __restrict__ q,
                                                   int* __restrict__ q8) {
  const int t = threadIdx.x;
  if (blockIdx.x >= M_ROWS) {
    const int i = (blockIdx.x - M_ROWS) * 256 + t;
    const int4 v = q[i];
    q8[i] = (v.x & 0xff) | ((v.y & 0xff) << 8) | ((v.z & 0xff) << 16) | (v.w << 24);
    return;
  }
  const int row = blockIdx.x;
  const float4* xr = x + (size_t)row * (K_DIM / 4);
  float4 v[4];
  float am = 0.f;
#pragma unroll
  for (int j = 0; j < 4; ++j) {
    v[j] = xr[t + 256 * j];
    am = fmaxf(am, fmaxf(fmaxf(fabsf(v[j].x), fabsf(v[j].y)),
                         fmaxf(fabsf(v[j].z), fabsf(v[j].w))));
  }
#pragma unroll
  for (int off = 32; off > 0; off >>= 1)
    am = fmaxf(am, __shfl_down(am, off, 64));
  __shared__ float wmax[4];
  if ((t & 63) == 0) wmax[t >> 6] = am;
  __syncthreads();
  am = fmaxf(fmaxf(wmax[0], wmax[1]), fmaxf(wmax[2], wmax[3]));
  const float s   = am * (1.f / 127.f);
  const float inv = (am > 0.f) ? 127.f / am : 0.f;
  if (t == 0) srow[row] = s;
  int* o = xq + (size_t)row * (K_DIM / 4);
#pragma unroll
  for (int j = 0; j < 4; ++j) {
    int a = __float2int_rn(v[j].x * inv);
    int b = __float2int_rn(v[j].y * inv);
    int c = __float2int_rn(v[j].z * inv);
    int d = __float2int_rn(v[j].w * inv);
    o[t + 256 * j] = (a & 0xff) | ((b & 0xff) << 8) | ((c & 0xff) << 16) | (d << 24);
  }
}

// ---- GEMM: A[M,K] int8 row-major, B[N,K] int8 row-major (B^T form) ----
__global__ __launch_bounds__(512, 2) void gemm_i8_kernel(
    const char* __restrict__ A, const char* __restrict__ B,
    const float* __restrict__ scale, const float* __restrict__ srow,
    const float* __restrict__ bias, float* __restrict__ out) {
  __shared__ __attribute__((aligned(16))) char sA[2][32768];
  __shared__ __attribute__((aligned(16))) char sB[2][32768];

  const int tid  = threadIdx.x;
  const int lane = tid & 63;
  const int w    = tid >> 6;     // 0..7
  const int wr   = w >> 2;       // 0..1 : M half (128 rows)
  const int wc   = w & 3;        // 0..3 : N quarter (64 cols)
  const int lm   = lane & 15;
  const int lk   = lane >> 4;

  // T1: bijective XCD swizzle (512 blocks % 8 == 0)
  const int bid = blockIdx.y * gridDim.x + blockIdx.x;
  const int lb  = (bid & 7) * 64 + (bid >> 3);
  const int m0  = (lb >> 4) * 256;   // 32 M-blocks
  const int n0  = (lb & 15) * 256;   // 16 N-blocks

  // ---- staging precompute: per q in {0,1}, one 16B chunk of each half ----
  // half-tile = 128 rows x 128B = 1024 chunks; 512 thr x 2 chunks.
  const char* srcA[2];  const char* srcB[2];
  int dstA[2], dstB[2];
#pragma unroll
  for (int q = 0; q < 2; ++q) {
    const int chq = q * 512 + tid;     // 0..1023
    const int cq  = chq & 7;           // stored col-chunk
    const int rl  = chq >> 3;          // 0..127 local row
    const int sw  = (cq ^ (rl & 7)) * 16;          // swizzled src col offset
    const int rA0 = (rl & 63) + ((rl >> 6) << 7);  // {0-63, 128-191}
    const int rB0 = (rl & 31) + ((rl >> 5) << 6);  // {0-31,64-95,128-159,192-223}
    srcA[q] = A + (size_t)(m0 + rA0) * K_DIM + sw;
    srcB[q] = B + (size_t)(n0 + rB0) * K_DIM + sw;
    dstA[q] = rA0 * 128 + cq * 16;
    dstB[q] = rB0 * 128 + cq * 16;
  }
  // derived halves: A'1 = A'0 rows +64 (src +64*K, dst +8192); B'1 = +32 rows.

#define ST_A0(b, k0) { async16(srcA[0] + (k0), &sA[b][dstA[0]]);                 \
                       async16(srcA[1] + (k0), &sA[b][dstA[1]]); }
#define ST_A1(b, k0) { async16(srcA[0] + (size_t)64 * K_DIM + (k0),              \
                               &sA[b][dstA[0] + 8192]);                          \
                       async16(srcA[1] + (size_t)64 * K_DIM + (k0),              \
                               &sA[b][dstA[1] + 8192]); }
#define ST_B0(b, k0) { async16(srcB[0] + (k0), &sB[b][dstB[0]]);                 \
                       async16(srcB[1] + (k0), &sB[b][dstB[1]]); }
#define ST_B1(b, k0) { async16(srcB[0] + (size_t)32 * K_DIM + (k0),              \
                               &sB[b][dstB[0] + 4096]);                          \
                       async16(srcB[1] + (size_t)32 * K_DIM + (k0),              \
                               &sB[b][dstB[1] + 4096]); }
#define BAR() { asm volatile("" ::: "memory"); __builtin_amdgcn_s_barrier();     \
                asm volatile("" ::: "memory"); }

  // read-side bases (bytes); row&7 == lm&7 for every fragment row.
  const int aOff = (wr * 128 + lm) * 128;
  const int bOff = (wc * 64 + lm) * 128;
  const int swz0 = (lk ^ (lm & 7)) * 16;
  const int swz1 = ((4 + lk) ^ (lm & 7)) * 16;

  int32x4 acc[8][4];
#pragma unroll
  for (int i = 0; i < 8; ++i)
#pragma unroll
    for (int j = 0; j < 4; ++j) acc[i][j] = (int32x4){0, 0, 0, 0};

  int32x4 af[2][4], b01[2][2], b23[2][2];

#define LD_A(MH)                                                                 \
  _Pragma("unroll") for (int ks = 0; ks < 2; ++ks)                               \
  _Pragma("unroll") for (int ii = 0; ii < 4; ++ii)                               \
    af[ks][ii] = *(const int32x4*)(&sA[buf][aOff + (MH) * 8192 + ii * 2048 +     \
                                            (ks ? swz1 : swz0)]);
#define LD_B(DST, JOFF)                                                          \
  _Pragma("unroll") for (int ks = 0; ks < 2; ++ks)                               \
  _Pragma("unroll") for (int j = 0; j < 2; ++j)                                  \
    DST[ks][j] = *(const int32x4*)(&sB[buf][bOff + ((JOFF) + j) * 2048 +         \
                                            (ks ? swz1 : swz0)]);
#define PH_MFMA(IOFF, JOFF, BF)                                                  \
  __builtin_amdgcn_s_setprio(1);                                                 \
  _Pragma("unroll") for (int ks = 0; ks < 2; ++ks)                               \
  _Pragma("unroll") for (int ii = 0; ii < 4; ++ii)                               \
  _Pragma("unroll") for (int j = 0; j < 2; ++j)                                  \
    acc[(IOFF) + ii][(JOFF) + j] = __builtin_amdgcn_mfma_i32_16x16x64_i8(        \
        af[ks][ii], BF[ks][j], acc[(IOFF) + ii][(JOFF) + j], 0, 0, 0);           \
  __builtin_amdgcn_s_setprio(0);

  // ---- prologue: tile0 (4 halves) + tile1 (3 halves); 3 halves stay in flight
  ST_A0(0, 0); ST_B0(0, 0); ST_B1(0, 0); ST_A1(0, 0);
  ST_A0(1, 128); ST_B0(1, 128); ST_B1(1, 128);
  asm volatile("s_waitcnt vmcnt(6)" ::: "memory");
  BAR();

  for (int t = 0; t < NT; ++t) {
    const int buf = t & 1;
    const int nb  = buf ^ 1;
    const int kk  = (t + 2) * 128;
    // ---- phase 1: quadrant (mh0, nh0); stage A'1(t+1) into other buffer ----
    LD_A(0);
    LD_B(b01, 0);
    if (t + 1 < NT) ST_A1(nb, (t + 1) * 128);
    BAR();
    PH_MFMA(0, 0, b01);
    BAR();
    // ---- phase 2: (mh0, nh1); stage A'0(t+2) (slot died at p1 barrier) ----
    LD_B(b23, 2);
    if (t + 2 < NT) ST_A0(buf, kk);
    BAR();
    PH_MFMA(0, 2, b23);
    BAR();
    // ---- phase 3: (mh1, nh1); stage B'0(t+2) (slot died at p1 barrier) ----
    LD_A(1);
    if (t + 2 < NT) ST_B0(buf, kk);
    BAR();
    PH_MFMA(4, 2, b23);
    BAR();
    // ---- phase 4: (mh1, nh0); stage B'1(t+2); counted vmcnt ----
    if (t + 2 < NT) {
      ST_B1(buf, kk);
      asm volatile("s_waitcnt vmcnt(6)" ::: "memory");
    } else {
      asm volatile("s_waitcnt vmcnt(0)" ::: "memory");
    }
    BAR();
    PH_MFMA(4, 0, b01);
    BAR();
  }

  // epilogue: C/D layout col=lane&15 (n), row=(lane>>4)*4+reg (m) — verified.
#pragma unroll
  for (int j = 0; j < 4; ++j) {
    const int o    = n0 + wc * 64 + j * 16 + lm;
    const float so = scale[o];
    const float bz = bias[o];
#pragma unroll
    for (int i = 0; i < 8; ++i) {
      const int mbase = m0 + wr * 128 + i * 16 + lk * 4;
#pragma unroll
      for (int r = 0; r < 4; ++r) {
        const int m = mbase + r;
        out[(size_t)m * N_COLS + o] = (float)acc[i][j][r] * (so * srow[m]) + bz;
      }
    }
  }
#undef ST_A0
#undef ST_A1
#undef ST_B0
#undef ST_B1
#undef BAR
#undef LD_A
#undef LD_B
#undef PH_MFMA
}

extern "C" void kernel_launch(void* const* d_in, const int* in_sizes, int n_in,
                              void* d_out, int out_size, void* d_ws, size_t ws_size,
                              hipStream_t stream) {
  const float* x     = (const float*)d_in[0];   // [4,2048,4096] fp32
  const int*   q     = (const int*)d_in[1];     // [4096,4096] int32 in [-8,7]
  const float* scale = (const float*)d_in[2];   // [4096]
  const float* bias  = (const float*)d_in[3];   // [4096]
  float* out = (float*)d_out;                   // [8192,4096] fp32

  // workspace: A8 (32 MiB) | B8 (16 MiB) | srow (32 KiB)
  char*  A8   = (char*)d_ws;
  char*  B8   = (char*)d_ws + (size_t)M_ROWS * K_DIM;
  float* srow = (float*)((char*)B8 + (size_t)N_COLS * K_DIM);

  const int cvt_blocks = (N_COLS * K_DIM / 4) / 256;   // 16384
  prep_kernel<<<M_ROWS + cvt_blocks, 256, 0, stream>>>(
      (const float4*)x, (int*)A8, srow, (const int4*)q, (int*)B8);

  dim3 grid(N_COLS / 256, M_ROWS / 256);  // 16 x 32 = 512 blocks
  gemm_i8_kernel<<<grid, 512, 0, stream>>>(A8, B8, scale, srow, bias, out);
}

// Round 3
// 412.443 us; speedup vs baseline: 1.0006x; 1.0006x over previous
//
#include <hip/hip_runtime.h>

// EdgeFormerINT4Linear via INT8 dynamic quantization:
// y[m,o] = (sum_i xq[m,i]*q[o,i]) * (srow[m]*scale[o]) + bias[o]
// Round 4: same verified 4-phase/256x256 staging skeleton as round 3
// (passed correctness; vmcnt(6) half-tile arithmetic unchanged), but every
// phase's incoming ds_reads are now issued in the PREVIOUS phase's MFMA
// shadow (post-MFMA, pre-barrier) instead of naked between barriers. i8's
// 2x-lower MFMA-per-LDS-byte ratio vs bf16 made the naked read window the
// dominant stall (~1000 cyc/phase -> 33% MfmaUtil at an invariant ~60us of
// MFMA-busy time).

#define M_ROWS 8192
#define N_COLS 4096
#define K_DIM  4096
#define NT     (K_DIM / 128)   // 32 K-tiles of 128 bytes

typedef int int32x4 __attribute__((ext_vector_type(4)));

__device__ __forceinline__ void async16(const void* g, void* l) {
  __builtin_amdgcn_global_load_lds(
      (const __attribute__((address_space(1))) void*)g,
      (__attribute__((address_space(3))) void*)l,
      16 /*bytes*/, 0 /*offset*/, 0 /*aux*/);
}

// ---- fused prepass ----
// blocks [0, M_ROWS): per-row symmetric int8 quant of x (256 thr x 16 elems)
// blocks [M_ROWS, ...): q int32 -> int8 pack (1 int4/thread)
__global__ __launch_bounds__(256) void prep_kernel(const float4* __restrict__ x,
                                                   int* __restrict__ xq,
                                                   float* __restrict__ srow,
                                                   const int4* __restrict__ q,
                                                   int* __restrict__ q8) {
  const int t = threadIdx.x;
  if (blockIdx.x >= M_ROWS) {
    const int i = (blockIdx.x - M_ROWS) * 256 + t;
    const int4 v = q[i];
    q8[i] = (v.x & 0xff) | ((v.y & 0xff) << 8) | ((v.z & 0xff) << 16) | (v.w << 24);
    return;
  }
  const int row = blockIdx.x;
  const float4* xr = x + (size_t)row * (K_DIM / 4);
  float4 v[4];
  float am = 0.f;
#pragma unroll
  for (int j = 0; j < 4; ++j) {
    v[j] = xr[t + 256 * j];
    am = fmaxf(am, fmaxf(fmaxf(fabsf(v[j].x), fabsf(v[j].y)),
                         fmaxf(fabsf(v[j].z), fabsf(v[j].w))));
  }
#pragma unroll
  for (int off = 32; off > 0; off >>= 1)
    am = fmaxf(am, __shfl_down(am, off, 64));
  __shared__ float wmax[4];
  if ((t & 63) == 0) wmax[t >> 6] = am;
  __syncthreads();
  am = fmaxf(fmaxf(wmax[0], wmax[1]), fmaxf(wmax[2], wmax[3]));
  const float s   = am * (1.f / 127.f);
  const float inv = (am > 0.f) ? 127.f / am : 0.f;
  if (t == 0) srow[row] = s;
  int* o = xq + (size_t)row * (K_DIM / 4);
#pragma unroll
  for (int j = 0; j < 4; ++j) {
    int a = __float2int_rn(v[j].x * inv);
    int b = __float2int_rn(v[j].y * inv);
    int c = __float2int_rn(v[j].z * inv);
    int d = __float2int_rn(v[j].w * inv);
    o[t + 256 * j] = (a & 0xff) | ((b & 0xff) << 8) | ((c & 0xff) << 16) | (d << 24);
  }
}

// ---- GEMM: A[M,K] int8 row-major, B[N,K] int8 row-major (B^T form) ----
__global__ __launch_bounds__(512, 2) void gemm_i8_kernel(
    const char* __restrict__ A, const char* __restrict__ B,
    const float* __restrict__ scale, const float* __restrict__ srow,
    const float* __restrict__ bias, float* __restrict__ out) {
  __shared__ __attribute__((aligned(16))) char sA[2][32768];
  __shared__ __attribute__((aligned(16))) char sB[2][32768];

  const int tid  = threadIdx.x;
  const int lane = tid & 63;
  const int w    = tid >> 6;     // 0..7
  const int wr   = w >> 2;       // 0..1 : M half (128 rows)
  const int wc   = w & 3;        // 0..3 : N quarter (64 cols)
  const int lm   = lane & 15;
  const int lk   = lane >> 4;

  // T1: bijective XCD swizzle (512 blocks % 8 == 0)
  const int bid = blockIdx.y * gridDim.x + blockIdx.x;
  const int lb  = (bid & 7) * 64 + (bid >> 3);
  const int m0  = (lb >> 4) * 256;   // 32 M-blocks
  const int n0  = (lb & 15) * 256;   // 16 N-blocks

  // ---- staging precompute: per q in {0,1}, one 16B chunk of each half ----
  // half-tile = 128 rows x 128B = 1024 chunks; 512 thr x 2 chunks.
  const char* srcA[2];  const char* srcB[2];
  int dstA[2], dstB[2];
#pragma unroll
  for (int q = 0; q < 2; ++q) {
    const int chq = q * 512 + tid;     // 0..1023
    const int cq  = chq & 7;           // stored col-chunk
    const int rl  = chq >> 3;          // 0..127 local row
    const int sw  = (cq ^ (rl & 7)) * 16;          // swizzled src col offset
    const int rA0 = (rl & 63) + ((rl >> 6) << 7);  // {0-63, 128-191}
    const int rB0 = (rl & 31) + ((rl >> 5) << 6);  // {0-31,64-95,128-159,192-223}
    srcA[q] = A + (size_t)(m0 + rA0) * K_DIM + sw;
    srcB[q] = B + (size_t)(n0 + rB0) * K_DIM + sw;
    dstA[q] = rA0 * 128 + cq * 16;
    dstB[q] = rB0 * 128 + cq * 16;
  }
  // derived halves: A'1 = A'0 rows +64 (src +64*K, dst +8192); B'1 = +32 rows.

#define ST_A0(b, k0) { async16(srcA[0] + (k0), &sA[b][dstA[0]]);                 \
                       async16(srcA[1] + (k0), &sA[b][dstA[1]]); }
#define ST_A1(b, k0) { async16(srcA[0] + (size_t)64 * K_DIM + (k0),              \
                               &sA[b][dstA[0] + 8192]);                          \
                       async16(srcA[1] + (size_t)64 * K_DIM + (k0),              \
                               &sA[b][dstA[1] + 8192]); }
#define ST_B0(b, k0) { async16(srcB[0] + (k0), &sB[b][dstB[0]]);                 \
                       async16(srcB[1] + (k0), &sB[b][dstB[1]]); }
#define ST_B1(b, k0) { async16(srcB[0] + (size_t)32 * K_DIM + (k0),              \
                               &sB[b][dstB[0] + 4096]);                          \
                       async16(srcB[1] + (size_t)32 * K_DIM + (k0),              \
                               &sB[b][dstB[1] + 4096]); }
#define BAR() { asm volatile("" ::: "memory"); __builtin_amdgcn_s_barrier();     \
                asm volatile("" ::: "memory"); }

  // read-side bases (bytes); row&7 == lm&7 for every fragment row.
  const int aOff = (wr * 128 + lm) * 128;
  const int bOff = (wc * 64 + lm) * 128;
  const int swz0 = (lk ^ (lm & 7)) * 16;
  const int swz1 = ((4 + lk) ^ (lm & 7)) * 16;

  int32x4 acc[8][4];
#pragma unroll
  for (int i = 0; i < 8; ++i)
#pragma unroll
    for (int j = 0; j < 4; ++j) acc[i][j] = (int32x4){0, 0, 0, 0};

  int32x4 af[2][4], b01[2][2], b23[2][2];

#define LD_A(BUF, MH)                                                            \
  _Pragma("unroll") for (int ks = 0; ks < 2; ++ks)                               \
  _Pragma("unroll") for (int ii = 0; ii < 4; ++ii)                               \
    af[ks][ii] = *(const int32x4*)(&sA[BUF][aOff + (MH) * 8192 + ii * 2048 +     \
                                            (ks ? swz1 : swz0)]);
#define LD_B(BUF, DST, JOFF)                                                     \
  _Pragma("unroll") for (int ks = 0; ks < 2; ++ks)                               \
  _Pragma("unroll") for (int j = 0; j < 2; ++j)                                  \
    DST[ks][j] = *(const int32x4*)(&sB[BUF][bOff + ((JOFF) + j) * 2048 +         \
                                            (ks ? swz1 : swz0)]);
#define PH_MFMA(IOFF, JOFF, BF)                                                  \
  __builtin_amdgcn_s_setprio(1);                                                 \
  _Pragma("unroll") for (int ks = 0; ks < 2; ++ks)                               \
  _Pragma("unroll") for (int ii = 0; ii < 4; ++ii)                               \
  _Pragma("unroll") for (int j = 0; j < 2; ++j)                                  \
    acc[(IOFF) + ii][(JOFF) + j] = __builtin_amdgcn_mfma_i32_16x16x64_i8(        \
        af[ks][ii], BF[ks][j], acc[(IOFF) + ii][(JOFF) + j], 0, 0, 0);           \
  __builtin_amdgcn_s_setprio(0);

  // ---- prologue: tile0 (4 halves) + tile1 (3 halves); 3 halves stay in flight
  ST_A0(0, 0); ST_B0(0, 0); ST_B1(0, 0); ST_A1(0, 0);
  ST_A0(1, 128); ST_B0(1, 128); ST_B1(1, 128);
  asm volatile("s_waitcnt vmcnt(6)" ::: "memory");
  BAR();
  // initial register prefetch for p1 of tile 0 (tile0 fully in LDS)
  LD_A(0, 0);
  LD_B(0, b01, 0);

  for (int t = 0; t < NT; ++t) {
    const int buf = t & 1;
    const int nb  = buf ^ 1;
    const int kk  = (t + 2) * 128;
    // ---- phase 1: MFMA (mh0,nh0) on prefetched af/b01; load b23 in shadow --
    if (t + 1 < NT) ST_A1(nb, (t + 1) * 128);
    BAR();
    PH_MFMA(0, 0, b01);
    LD_B(buf, b23, 2);          // incoming for p2 (b23 dead since p3(t-1))
    BAR();
    // ---- phase 2: MFMA (mh0,nh1); load af<-mh1 in shadow (WAR-safe) --------
    if (t + 2 < NT) ST_A0(buf, kk);
    BAR();
    PH_MFMA(0, 2, b23);
    LD_A(buf, 1);               // incoming for p3/p4 (af mh0 last used above)
    BAR();
    // ---- phase 3: MFMA (mh1,nh1); no incoming reads ------------------------
    if (t + 2 < NT) ST_B0(buf, kk);
    BAR();
    PH_MFMA(4, 2, b23);
    BAR();
    // ---- phase 4: MFMA (mh1,nh0); counted vmcnt; next-tile reads in shadow -
    if (t + 2 < NT) {
      ST_B1(buf, kk);
      asm volatile("s_waitcnt vmcnt(6)" ::: "memory");
    } else {
      asm volatile("s_waitcnt vmcnt(0)" ::: "memory");
    }
    BAR();
    PH_MFMA(4, 0, b01);
    if (t + 1 < NT) {           // tile t+1 fully in LDS (vmcnt above retired
      LD_A(nb, 0);              // through A'1(t+1)); af/b01 WAR-safe after p4
      LD_B(nb, b01, 0);
    }
    BAR();
  }

  // epilogue: C/D layout col=lane&15 (n), row=(lane>>4)*4+reg (m) — verified.
#pragma unroll
  for (int j = 0; j < 4; ++j) {
    const int o    = n0 + wc * 64 + j * 16 + lm;
    const float so = scale[o];
    const float bz = bias[o];
#pragma unroll
    for (int i = 0; i < 8; ++i) {
      const int mbase = m0 + wr * 128 + i * 16 + lk * 4;
#pragma unroll
      for (int r = 0; r < 4; ++r) {
        const int m = mbase + r;
        out[(size_t)m * N_COLS + o] = (float)acc[i][j][r] * (so * srow[m]) + bz;
      }
    }
  }
#undef ST_A0
#undef ST_A1
#undef ST_B0
#undef ST_B1
#undef BAR
#undef LD_A
#undef LD_B
#undef PH_MFMA
}

extern "C" void kernel_launch(void* const* d_in, const int* in_sizes, int n_in,
                              void* d_out, int out_size, void* d_ws, size_t ws_size,
                              hipStream_t stream) {
  const float* x     = (const float*)d_in[0];   // [4,2048,4096] fp32
  const int*   q     = (const int*)d_in[1];     // [4096,4096] int32 in [-8,7]
  const float* scale = (const float*)d_in[2];   // [4096]
  const float* bias  = (const float*)d_in[3];   // [4096]
  float* out = (float*)d_out;                   // [8192,4096] fp32

  // workspace: A8 (32 MiB) | B8 (16 MiB) | srow (32 KiB)
  char*  A8   = (char*)d_ws;
  char*  B8   = (char*)d_ws + (size_t)M_ROWS * K_DIM;
  float* srow = (float*)((char*)B8 + (size_t)N_COLS * K_DIM);

  const int cvt_blocks = (N_COLS * K_DIM / 4) / 256;   // 16384
  prep_kernel<<<M_ROWS + cvt_blocks, 256, 0, stream>>>(
      (const float4*)x, (int*)A8, srow, (const int4*)q, (int*)B8);

  dim3 grid(N_COLS / 256, M_ROWS / 256);  // 16 x 32 = 512 blocks
  gemm_i8_kernel<<<grid, 512, 0, stream>>>(A8, B8, scale, srow, bias, out);
}

// Round 4
// 406.254 us; speedup vs baseline: 1.0158x; 1.0152x over previous
//
#include <hip/hip_runtime.h>

// EdgeFormerINT4Linear via INT8 dynamic quantization:
// y[m,o] = (sum_i xq[m,i]*q[o,i]) * (srow[m]*scale[o]) + bias[o]
// Round 5: REVERT gemm to the round-0 proven structure (128x128 tile, 4
// waves, single-buffer LDS, 2-barrier K-loop, 3-4 blocks/CU inter-block
// overlap — 136us measured) + T1 bijective XCD swizzle (2048%8==0; each XCD
// gets 8 contiguous M-panels x all N -> L2 temporal locality; FETCH_SIZE is
// the readout). Fused prep kept (verified -18us vs split). The 256x256
// 8-phase ports (R1-R3) never beat this structure: MFMA-busy time was
// invariant ~60us in all variants; the 256^2/1-block schedules only added
// naked non-MFMA time. Do NOT raise launch_bounds min-waves: 64 AGPR acc +
// 64 VGPR = 128 unified regs = exactly the 4-wave/SIMD budget; requesting 5
// blocks/CU would force spills.

#define M_ROWS 8192
#define N_COLS 4096
#define K_DIM  4096

typedef int int32x4 __attribute__((ext_vector_type(4)));

__device__ __forceinline__ void async16(const void* g, void* l) {
  __builtin_amdgcn_global_load_lds(
      (const __attribute__((address_space(1))) void*)g,
      (__attribute__((address_space(3))) void*)l,
      16 /*bytes*/, 0 /*offset*/, 0 /*aux*/);
}

// ---- fused prepass ----
// blocks [0, M_ROWS): per-row symmetric int8 quant of x (256 thr x 16 elems)
// blocks [M_ROWS, ...): q int32 -> int8 pack (1 int4/thread)
__global__ __launch_bounds__(256) void prep_kernel(const float4* __restrict__ x,
                                                   int* __restrict__ xq,
                                                   float* __restrict__ srow,
                                                   const int4* __restrict__ q,
                                                   int* __restrict__ q8) {
  const int t = threadIdx.x;
  if (blockIdx.x >= M_ROWS) {
    const int i = (blockIdx.x - M_ROWS) * 256 + t;
    const int4 v = q[i];
    q8[i] = (v.x & 0xff) | ((v.y & 0xff) << 8) | ((v.z & 0xff) << 16) | (v.w << 24);
    return;
  }
  const int row = blockIdx.x;
  const float4* xr = x + (size_t)row * (K_DIM / 4);
  float4 v[4];
  float am = 0.f;
#pragma unroll
  for (int j = 0; j < 4; ++j) {
    v[j] = xr[t + 256 * j];
    am = fmaxf(am, fmaxf(fmaxf(fabsf(v[j].x), fabsf(v[j].y)),
                         fmaxf(fabsf(v[j].z), fabsf(v[j].w))));
  }
#pragma unroll
  for (int off = 32; off > 0; off >>= 1)
    am = fmaxf(am, __shfl_down(am, off, 64));
  __shared__ float wmax[4];
  if ((t & 63) == 0) wmax[t >> 6] = am;
  __syncthreads();
  am = fmaxf(fmaxf(wmax[0], wmax[1]), fmaxf(wmax[2], wmax[3]));
  const float s   = am * (1.f / 127.f);
  const float inv = (am > 0.f) ? 127.f / am : 0.f;
  if (t == 0) srow[row] = s;
  int* o = xq + (size_t)row * (K_DIM / 4);
#pragma unroll
  for (int j = 0; j < 4; ++j) {
    int a = __float2int_rn(v[j].x * inv);
    int b = __float2int_rn(v[j].y * inv);
    int c = __float2int_rn(v[j].z * inv);
    int d = __float2int_rn(v[j].w * inv);
    o[t + 256 * j] = (a & 0xff) | ((b & 0xff) << 8) | ((c & 0xff) << 16) | (d << 24);
  }
}

// ---- GEMM: A[M,K] int8 row-major, B[N,K] int8 row-major (B^T form) ----
// Block = 256 threads (4 waves), tile 128x128, BK=128 (128 B per tile row =
// 8 chunks of 16B). Each wave: 4x4 grid of 16x16x64 i8 MFMAs, 2 per
// K-sub-step. Verified XOR-chunk swizzle (0 bank conflicts, 4 rounds).
__global__ __launch_bounds__(256, 4) void gemm_i8_kernel(
    const char* __restrict__ A, const char* __restrict__ B,
    const float* __restrict__ scale, const float* __restrict__ srow,
    const float* __restrict__ bias, float* __restrict__ out) {
  __shared__ __attribute__((aligned(16))) char sA[128 * 128];
  __shared__ __attribute__((aligned(16))) char sB[128 * 128];

  const int tid  = threadIdx.x;
  const int lane = tid & 63;
  const int w    = tid >> 6;
  const int wr   = w >> 1;
  const int wc   = w & 1;
  const int lm   = lane & 15;   // m (A) / n (B) / col (C)
  const int lk   = lane >> 4;   // k-group 0..3

  // T1: bijective XCD swizzle. 2048 blocks, 8 XCDs -> 256 blocks/XCD, each
  // XCD chunk = 8 contiguous M-panels x all 32 N-panels.
  const int bid = blockIdx.y * gridDim.x + blockIdx.x;   // 0..2047
  const int swz = (bid & 7) * 256 + (bid >> 3);
  const int m0  = (swz >> 5) * 128;   // 64 M-panels
  const int n0  = (swz & 31) * 128;   // 32 N-panels

  int32x4 acc[4][4];
#pragma unroll
  for (int i = 0; i < 4; ++i)
#pragma unroll
    for (int j = 0; j < 4; ++j)
      acc[i][j] = (int32x4){0, 0, 0, 0};

  for (int it = 0; it < K_DIM / 128; ++it) {
    const int k0 = it * 128;   // byte offset within a row (1 int8 = 1 byte)
#pragma unroll
    for (int i = 0; i < 4; ++i) {
      const int ch = i * 256 + tid;          // chunk 0..1023
      const int r  = ch >> 3;                // tile row 0..127
      const int sc = (ch & 7) ^ (r & 7);     // swizzled source col-chunk
      async16(A + (size_t)(m0 + r) * K_DIM + k0 + sc * 16, sA + ch * 16);
      async16(B + (size_t)(n0 + r) * K_DIM + k0 + sc * 16, sB + ch * 16);
    }
    __syncthreads();

#pragma unroll
    for (int ks = 0; ks < 2; ++ks) {
      int32x4 af[4], bfr[4];
      const int kc = ks * 4 + lk;            // 16B-chunk 0..7 within BK=128
#pragma unroll
      for (int i = 0; i < 4; ++i) {
        const int row = wr * 64 + i * 16 + lm;
        af[i] = *(const int32x4*)(sA + ((row * 8) + (kc ^ (row & 7))) * 16);
      }
#pragma unroll
      for (int j = 0; j < 4; ++j) {
        const int row = wc * 64 + j * 16 + lm;
        bfr[j] = *(const int32x4*)(sB + ((row * 8) + (kc ^ (row & 7))) * 16);
      }
#pragma unroll
      for (int i = 0; i < 4; ++i)
#pragma unroll
        for (int j = 0; j < 4; ++j)
          acc[i][j] = __builtin_amdgcn_mfma_i32_16x16x64_i8(af[i], bfr[j],
                                                            acc[i][j], 0, 0, 0);
    }
    __syncthreads();
  }

  // epilogue: C/D layout col=lane&15 (n), row=(lane>>4)*4+reg (m)
#pragma unroll
  for (int j = 0; j < 4; ++j) {
    const int o    = n0 + wc * 64 + j * 16 + lm;
    const float so = scale[o];
    const float bz = bias[o];
#pragma unroll
    for (int i = 0; i < 4; ++i) {
      const int mbase = m0 + wr * 64 + i * 16 + lk * 4;
#pragma unroll
      for (int r = 0; r < 4; ++r) {
        const int m = mbase + r;
        out[(size_t)m * N_COLS + o] = (float)acc[i][j][r] * (so * srow[m]) + bz;
      }
    }
  }
}

extern "C" void kernel_launch(void* const* d_in, const int* in_sizes, int n_in,
                              void* d_out, int out_size, void* d_ws, size_t ws_size,
                              hipStream_t stream) {
  const float* x     = (const float*)d_in[0];   // [4,2048,4096] fp32
  const int*   q     = (const int*)d_in[1];     // [4096,4096] int32 in [-8,7]
  const float* scale = (const float*)d_in[2];   // [4096]
  const float* bias  = (const float*)d_in[3];   // [4096]
  float* out = (float*)d_out;                   // [8192,4096] fp32

  // workspace: A8 (32 MiB) | B8 (16 MiB) | srow (32 KiB)
  char*  A8   = (char*)d_ws;
  char*  B8   = (char*)d_ws + (size_t)M_ROWS * K_DIM;
  float* srow = (float*)((char*)B8 + (size_t)N_COLS * K_DIM);

  const int cvt_blocks = (N_COLS * K_DIM / 4) / 256;   // 16384
  prep_kernel<<<M_ROWS + cvt_blocks, 256, 0, stream>>>(
      (const float4*)x, (int*)A8, srow, (const int4*)q, (int*)B8);

  dim3 grid(N_COLS / 128, M_ROWS / 128);  // 32 x 64 = 2048 blocks
  gemm_i8_kernel<<<grid, 256, 0, stream>>>(A8, B8, scale, srow, bias, out);
}